// Round 3
// baseline (631.085 us; speedup 1.0000x reference)
//
#include <hip/hip_runtime.h>
#include <math.h>

#define N_REL  8
#define IN_CH  16
#define HID_CH 32
#define OUT_CH 2
#define NB     8      // nodes per half-wave in l1 (wave handles 16 nodes)

// ---------------------------------------------------------------------------
// count: per-(dst,rel) edge counts into ptr[] (later scanned in place)
// ---------------------------------------------------------------------------
__global__ void count_kernel(const int* __restrict__ dst,
                             const int* __restrict__ rel,
                             int* __restrict__ ptr, int E) {
    int e = blockIdx.x * blockDim.x + threadIdx.x;
    if (e < E) atomicAdd(&ptr[dst[e] * N_REL + rel[e]], 1);
}

// ---------------------------------------------------------------------------
// scan_a: in-place per-block (1024) exclusive scan of ptr[0..M); blksum[b]=total
// ---------------------------------------------------------------------------
__global__ __launch_bounds__(1024) void scan_a_kernel(int* __restrict__ ptr,
                                                      int* __restrict__ blksum, int M) {
    int i = blockIdx.x * 1024 + threadIdx.x;
    int val = (i < M) ? ptr[i] : 0;
    int lane = threadIdx.x & 63;
    int wid  = threadIdx.x >> 6;

    int v = val;
#pragma unroll
    for (int off = 1; off < 64; off <<= 1) {
        int u = __shfl_up(v, off, 64);
        if (lane >= off) v += u;
    }

    __shared__ int wsum[16];
    if (lane == 63) wsum[wid] = v;
    __syncthreads();

    if (wid == 0) {
        int worig = (lane < 16) ? wsum[lane] : 0;
        int wv = worig;
#pragma unroll
        for (int off = 1; off < 16; off <<= 1) {
            int u = __shfl_up(wv, off, 64);
            if (lane >= off) wv += u;
        }
        if (lane < 16) wsum[lane] = wv - worig;
        if (lane == 15) blksum[blockIdx.x] = wv;
    }
    __syncthreads();

    if (i < M) ptr[i] = (v - val) + wsum[wid];
}

// ---------------------------------------------------------------------------
// scan_b: single wave scans the block sums (exclusive, in place)
// ---------------------------------------------------------------------------
__global__ void scan_b_kernel(int* __restrict__ blksum, int nb) {
    int lane = threadIdx.x & 63;
    int run = 0;
    for (int base = 0; base < nb; base += 64) {
        int i = base + lane;
        int val = (i < nb) ? blksum[i] : 0;
        int v = val;
#pragma unroll
        for (int off = 1; off < 64; off <<= 1) {
            int u = __shfl_up(v, off, 64);
            if (lane >= off) v += u;
        }
        if (i < nb) blksum[i] = run + (v - val);
        run += __shfl(v, 63, 64);
    }
}

// ---------------------------------------------------------------------------
// scan_c: add block offsets
// ---------------------------------------------------------------------------
__global__ __launch_bounds__(1024) void scan_c_kernel(int* __restrict__ ptr,
                                                      const int* __restrict__ blksum, int M) {
    int i = blockIdx.x * 1024 + threadIdx.x;
    if (i < M) ptr[i] += blksum[blockIdx.x];
}

// ---------------------------------------------------------------------------
// fill: csr[slot]=src, bumping ptr so that afterwards ptr[i] = END of segment i
// ---------------------------------------------------------------------------
__global__ void fill_kernel(const int* __restrict__ src,
                            const int* __restrict__ dst,
                            const int* __restrict__ rel,
                            int* __restrict__ ptr,
                            int* __restrict__ csr, int E) {
    int e = blockIdx.x * blockDim.x + threadIdx.x;
    if (e >= E) return;
    int slot = atomicAdd(&ptr[dst[e] * N_REL + rel[e]], 1);
    csr[slot] = src[e];
}

// ---------------------------------------------------------------------------
// prep: transpose W1 [r][f][c] -> W1T [r][c][f];  root1 [f][c] -> root1T [c][f]
// ---------------------------------------------------------------------------
__global__ void prep_kernel(const float* __restrict__ W1,
                            const float* __restrict__ root1,
                            float* __restrict__ W1T,
                            float* __restrict__ root1T) {
    for (int i = threadIdx.x; i < N_REL * IN_CH * HID_CH; i += blockDim.x) {
        int r = i >> 9, rem = i & 511;
        int c = rem >> 4, f = rem & 15;
        W1T[i] = W1[r * 512 + f * 32 + c];
    }
    for (int i = threadIdx.x; i < IN_CH * HID_CH; i += blockDim.x) {
        int c = i >> 4, f = i & 15;
        root1T[i] = root1[f * 32 + c];
    }
}

// ---------------------------------------------------------------------------
// l1: wave = 16 nodes (8 per half-wave), lane&31 = hidden channel.
// For r in 0..7: weights for (r, c) in 4 float4 regs; process each node's
// r-segment of the rel-sorted CSR. norm = 1/seglen. No LDS, no atomics.
// ---------------------------------------------------------------------------
__global__ __launch_bounds__(256) void l1_kernel(const float* __restrict__ x,
                                                 const int* __restrict__ csr,
                                                 const int* __restrict__ ends,
                                                 const float* __restrict__ W1T,
                                                 const float* __restrict__ root1T,
                                                 const float* __restrict__ b1,
                                                 float* __restrict__ h, int N) {
    int lane = threadIdx.x & 63;
    int wv   = (blockIdx.x * 256 + threadIdx.x) >> 6;
    int half = lane >> 5;
    int c    = lane & 31;
    int node0 = wv * (2 * NB) + half * NB;

    float acc[NB];
    int   prev[NB];
#pragma unroll
    for (int b = 0; b < NB; ++b) {
        acc[b] = 0.0f;
        int n = node0 + b;
        prev[b] = (n > 0 && n < N) ? ends[n * N_REL - 1] : 0;
    }

    for (int r = 0; r < N_REL; ++r) {
        const float4* wr = (const float4*)(W1T + ((r * 32 + c) << 4));
        float4 w0 = wr[0], w1 = wr[1], w2 = wr[2], w3 = wr[3];

#pragma unroll
        for (int b = 0; b < NB; ++b) {
            int n = node0 + b;
            if (n >= N) break;
            int end = ends[n * N_REL + r];
            int len = end - prev[b];
            if (len > 0) {
                float msA = 0.0f, msB = 0.0f;
                for (int p = prev[b]; p < end; ++p) {
                    int s = csr[p];
                    const float4* xs = (const float4*)(x + ((long)s << 4));
                    float4 v0 = xs[0], v1 = xs[1], v2 = xs[2], v3 = xs[3];
                    float a = 0.0f, bb = 0.0f;
                    a  += v0.x * w0.x; a  += v0.y * w0.y; a  += v0.z * w0.z; a  += v0.w * w0.w;
                    a  += v1.x * w1.x; a  += v1.y * w1.y; a  += v1.z * w1.z; a  += v1.w * w1.w;
                    bb += v2.x * w2.x; bb += v2.y * w2.y; bb += v2.z * w2.z; bb += v2.w * w2.w;
                    bb += v3.x * w3.x; bb += v3.y * w3.y; bb += v3.z * w3.z; bb += v3.w * w3.w;
                    msA += a; msB += bb;
                }
                acc[b] += (msA + msB) * (1.0f / (float)len);
                prev[b] = end;
            }
        }
    }

    // root term + bias + relu + store
    const float4* rr = (const float4*)(root1T + (c << 4));
    float4 r0 = rr[0], r1 = rr[1], r2 = rr[2], r3 = rr[3];
    float bias = b1[c];
#pragma unroll
    for (int b = 0; b < NB; ++b) {
        int n = node0 + b;
        if (n >= N) break;
        const float4* xs = (const float4*)(x + ((long)n << 4));
        float4 v0 = xs[0], v1 = xs[1], v2 = xs[2], v3 = xs[3];
        float a = acc[b] + bias;
        a += v0.x * r0.x + v0.y * r0.y + v0.z * r0.z + v0.w * r0.w;
        a += v1.x * r1.x + v1.y * r1.y + v1.z * r1.z + v1.w * r1.w;
        a += v2.x * r2.x + v2.y * r2.y + v2.z * r2.z + v2.w * r2.w;
        a += v3.x * r3.x + v3.y * r3.y + v3.z * r3.z + v3.w * r3.w;
        h[((long)n << 5) + c] = fmaxf(a, 0.0f);
    }
}

// ---------------------------------------------------------------------------
// l2: wave = 2 nodes, lane&31 = hidden channel; all 16 W2 weights in regs.
// ---------------------------------------------------------------------------
__global__ __launch_bounds__(256) void l2_kernel(const float* __restrict__ h,
                                                 const int* __restrict__ csr,
                                                 const int* __restrict__ ends,
                                                 const float* __restrict__ W2,
                                                 const float* __restrict__ root2,
                                                 const float* __restrict__ b2,
                                                 float* __restrict__ out, int N) {
    int lane = threadIdx.x & 63;
    int wv   = (blockIdx.x * 256 + threadIdx.x) >> 6;
    int half = lane >> 5;
    int c    = lane & 31;
    int n    = wv * 2 + half;

    float2 w[N_REL];
#pragma unroll
    for (int r = 0; r < N_REL; ++r)
        w[r] = *(const float2*)(W2 + ((r * 32 + c) << 1));

    if (n >= N) return;

    int prev = (n > 0) ? ends[n * N_REL - 1] : 0;
    float o0 = 0.0f, o1 = 0.0f;

#pragma unroll
    for (int r = 0; r < N_REL; ++r) {
        int end = ends[n * N_REL + r];
        int len = end - prev;
        if (len > 0) {
            float hsum = 0.0f;
            for (int p = prev; p < end; ++p) {
                int s = csr[p];
                hsum += h[((long)s << 5) + c];
            }
            float iv = 1.0f / (float)len;
            o0 += hsum * iv * w[r].x;
            o1 += hsum * iv * w[r].y;
            prev = end;
        }
    }

    // root term
    float hr = h[((long)n << 5) + c];
    float2 rt = *(const float2*)(root2 + (c << 1));
    o0 += hr * rt.x;
    o1 += hr * rt.y;

    // reduce across 32 lanes (xor masks < 32 stay within the half-wave)
#pragma unroll
    for (int m = 1; m < 32; m <<= 1) {
        o0 += __shfl_xor(o0, m, 64);
        o1 += __shfl_xor(o1, m, 64);
    }

    if (c == 0) {
        o0 += b2[0];
        o1 += b2[1];
        float mx = fmaxf(o0, o1);
        float l  = mx + logf(__expf(o0 - mx) + __expf(o1 - mx));
        *(float2*)(out + ((long)n << 1)) = make_float2(o0 - l, o1 - l);
    }
}

// ---------------------------------------------------------------------------
extern "C" void kernel_launch(void* const* d_in, const int* in_sizes, int n_in,
                              void* d_out, int out_size, void* d_ws, size_t ws_size,
                              hipStream_t stream) {
    const float* x     = (const float*)d_in[0];
    const int*   eidx  = (const int*)d_in[1];
    const int*   etype = (const int*)d_in[2];
    const float* W1    = (const float*)d_in[3];
    const float* root1 = (const float*)d_in[4];
    const float* b1    = (const float*)d_in[5];
    const float* W2    = (const float*)d_in[6];
    const float* root2 = (const float*)d_in[7];
    const float* b2    = (const float*)d_in[8];
    float* out = (float*)d_out;

    const int N = in_sizes[0] / IN_CH;
    const int E = in_sizes[2];
    const int M = N * N_REL;
    const int* src = eidx;
    const int* dst = eidx + E;

    // ws layout: ptr[M] | blksum[4096] | csr[E] | h[N*32] | W1T[4096] | root1T[512]
    char* wp = (char*)d_ws;
    auto take = [&](size_t bytes) {
        char* p = wp;
        wp += (bytes + 15) & ~(size_t)15;
        return p;
    };
    int*   ptr    = (int*)take((size_t)M * sizeof(int));
    int*   blksum = (int*)take(4096 * sizeof(int));
    int*   csr    = (int*)take((size_t)E * sizeof(int));
    float* h      = (float*)take((size_t)N * HID_CH * sizeof(float));
    float* W1T    = (float*)take((size_t)N_REL * IN_CH * HID_CH * sizeof(float));
    float* root1T = (float*)take((size_t)IN_CH * HID_CH * sizeof(float));

    hipMemsetAsync(ptr, 0, (size_t)M * sizeof(int), stream);

    const int B = 256;
    const int nb = (M + 1023) / 1024;

    prep_kernel<<<1, 1024, 0, stream>>>(W1, root1, W1T, root1T);
    count_kernel<<<(E + B - 1) / B, B, 0, stream>>>(dst, etype, ptr, E);
    scan_a_kernel<<<nb, 1024, 0, stream>>>(ptr, blksum, M);
    scan_b_kernel<<<1, 64, 0, stream>>>(blksum, nb);
    scan_c_kernel<<<nb, 1024, 0, stream>>>(ptr, blksum, M);
    fill_kernel<<<(E + B - 1) / B, B, 0, stream>>>(src, dst, etype, ptr, csr, E);

    {
        int waves = (N + 2 * NB - 1) / (2 * NB);
        int grid  = (waves + 3) / 4;           // 4 waves per 256-block
        l1_kernel<<<grid, B, 0, stream>>>(x, csr, ptr, W1T, root1T, b1, h, N);
    }
    {
        int waves = (N + 1) / 2;
        int grid  = (waves + 3) / 4;
        l2_kernel<<<grid, B, 0, stream>>>(h, csr, ptr, W2, root2, b2, out, N);
    }
}

// Round 4
// 361.720 us; speedup vs baseline: 1.7447x; 1.7447x over previous
//
#include <hip/hip_runtime.h>
#include <math.h>

#define N_REL  8
#define IN_CH  16
#define HID_CH 32
#define OUT_CH 2

// float -> bf16 round-to-nearest-even
static __device__ __forceinline__ unsigned short f2b(float f) {
    unsigned int u = __float_as_uint(f);
    u = (u + 0x7FFFu + ((u >> 16) & 1u)) >> 16;
    return (unsigned short)u;
}
static __device__ __forceinline__ float b2f(unsigned short s) {
    return __uint_as_float(((unsigned int)s) << 16);
}

// ---------------------------------------------------------------------------
// count: per-(dst,rel) edge counts into ptr[] (later scanned in place)
// ---------------------------------------------------------------------------
__global__ void count_kernel(const int* __restrict__ dst,
                             const int* __restrict__ rel,
                             int* __restrict__ ptr, int E) {
    int e = blockIdx.x * blockDim.x + threadIdx.x;
    if (e < E) atomicAdd(&ptr[dst[e] * N_REL + rel[e]], 1);
}

// ---------------------------------------------------------------------------
// scan_a/b/c: exclusive scan of ptr[0..M) (in place)
// ---------------------------------------------------------------------------
__global__ __launch_bounds__(1024) void scan_a_kernel(int* __restrict__ ptr,
                                                      int* __restrict__ blksum, int M) {
    int i = blockIdx.x * 1024 + threadIdx.x;
    int val = (i < M) ? ptr[i] : 0;
    int lane = threadIdx.x & 63;
    int wid  = threadIdx.x >> 6;

    int v = val;
#pragma unroll
    for (int off = 1; off < 64; off <<= 1) {
        int u = __shfl_up(v, off, 64);
        if (lane >= off) v += u;
    }

    __shared__ int wsum[16];
    if (lane == 63) wsum[wid] = v;
    __syncthreads();

    if (wid == 0) {
        int worig = (lane < 16) ? wsum[lane] : 0;
        int wv = worig;
#pragma unroll
        for (int off = 1; off < 16; off <<= 1) {
            int u = __shfl_up(wv, off, 64);
            if (lane >= off) wv += u;
        }
        if (lane < 16) wsum[lane] = wv - worig;
        if (lane == 15) blksum[blockIdx.x] = wv;
    }
    __syncthreads();

    if (i < M) ptr[i] = (v - val) + wsum[wid];
}

__global__ void scan_b_kernel(int* __restrict__ blksum, int nb) {
    int lane = threadIdx.x & 63;
    int run = 0;
    for (int base = 0; base < nb; base += 64) {
        int i = base + lane;
        int val = (i < nb) ? blksum[i] : 0;
        int v = val;
#pragma unroll
        for (int off = 1; off < 64; off <<= 1) {
            int u = __shfl_up(v, off, 64);
            if (lane >= off) v += u;
        }
        if (i < nb) blksum[i] = run + (v - val);
        run += __shfl(v, 63, 64);
    }
}

__global__ __launch_bounds__(1024) void scan_c_kernel(int* __restrict__ ptr,
                                                      const int* __restrict__ blksum, int M) {
    int i = blockIdx.x * 1024 + threadIdx.x;
    if (i < M) ptr[i] += blksum[blockIdx.x];
}

// ---------------------------------------------------------------------------
// fill: csr[slot]=src; afterwards ptr[i] = END of segment i (rel-sorted CSR)
// ---------------------------------------------------------------------------
__global__ void fill_kernel(const int* __restrict__ src,
                            const int* __restrict__ dst,
                            const int* __restrict__ rel,
                            int* __restrict__ ptr,
                            int* __restrict__ csr, int E) {
    int e = blockIdx.x * blockDim.x + threadIdx.x;
    if (e >= E) return;
    int slot = atomicAdd(&ptr[dst[e] * N_REL + rel[e]], 1);
    csr[slot] = src[e];
}

// ---------------------------------------------------------------------------
// xw: xW16[n][r][c] = bf16( x[n] @ W1[r][:,c] ).  Block=256 threads, thread=(r,c),
// weights hoisted to registers; 64-node tile of x staged in LDS.
// ---------------------------------------------------------------------------
#define XW_TILE 64
__global__ __launch_bounds__(256) void xw_kernel(const float* __restrict__ x,
                                                 const float* __restrict__ W1,
                                                 unsigned short* __restrict__ xW16, int N) {
    __shared__ float sx[XW_TILE * IN_CH];   // 4 KB
    int t = threadIdx.x;
    int node0 = blockIdx.x * XW_TILE;

    {   // stage tile (float4-coalesced), guard tail
        int i4 = node0 * 4 + t;             // global float4 index
        float4 v = make_float4(0.f, 0.f, 0.f, 0.f);
        if (i4 < N * 4) v = ((const float4*)x)[i4];
        ((float4*)sx)[t] = v;
    }
    __syncthreads();

    int r = t >> 5, c = t & 31;
    // weight column (r, c) in registers
    float w[IN_CH];
#pragma unroll
    for (int f = 0; f < IN_CH; ++f)
        w[f] = W1[(r * IN_CH + f) * HID_CH + c];

    int lim = N - node0; if (lim > XW_TILE) lim = XW_TILE;
    for (int ni = 0; ni < lim; ++ni) {
        const float4* xs = (const float4*)(sx + ni * IN_CH);
        float4 v0 = xs[0], v1 = xs[1], v2 = xs[2], v3 = xs[3];
        float a;
        a  = v0.x * w[0]  + v0.y * w[1]  + v0.z * w[2]  + v0.w * w[3];
        a += v1.x * w[4]  + v1.y * w[5]  + v1.z * w[6]  + v1.w * w[7];
        a += v2.x * w[8]  + v2.y * w[9]  + v2.z * w[10] + v2.w * w[11];
        a += v3.x * w[12] + v3.y * w[13] + v3.z * w[14] + v3.w * w[15];
        xW16[(node0 + ni) * (N_REL * HID_CH) + t] = f2b(a);
    }
}

// ---------------------------------------------------------------------------
// l1 gather: half-wave per node, lane = hidden channel c.
// h[n][c] = relu( b1[c] + x[n]@root1[:,c] + sum_r (1/len_r) sum_{s in seg_r} xW16[s][r][c] )
// ---------------------------------------------------------------------------
__global__ __launch_bounds__(256) void l1_gather_kernel(const float* __restrict__ x,
                                                        const int* __restrict__ csr,
                                                        const int* __restrict__ ends,
                                                        const unsigned short* __restrict__ xW16,
                                                        const float* __restrict__ root1,
                                                        const float* __restrict__ b1,
                                                        float* __restrict__ h, int N) {
    int gid  = blockIdx.x * 256 + threadIdx.x;
    int node = gid >> 5;
    int c    = gid & 31;
    if (node >= N) return;

    // all 8 segment ends in two int4 loads (32B-aligned)
    int4 e0 = ((const int4*)ends)[node * 2];
    int4 e1 = ((const int4*)ends)[node * 2 + 1];
    int end_r[N_REL] = {e0.x, e0.y, e0.z, e0.w, e1.x, e1.y, e1.z, e1.w};

    int prev = (node > 0) ? __ldg(&ends[node * N_REL - 1]) : 0;
    float acc = 0.0f;

#pragma unroll
    for (int r = 0; r < N_REL; ++r) {
        int end = end_r[r];
        int len = end - prev;
        if (len > 0) {
            float seg = 0.0f;
            int p = prev;
            for (; p + 1 < end; p += 2) {       // 2-way unroll: 2 loads in flight
                int s0 = csr[p], s1 = csr[p + 1];
                seg += b2f(xW16[((s0 << 3) + r) * HID_CH + c]);
                seg += b2f(xW16[((s1 << 3) + r) * HID_CH + c]);
            }
            if (p < end) {
                int s0 = csr[p];
                seg += b2f(xW16[((s0 << 3) + r) * HID_CH + c]);
            }
            acc += seg * (1.0f / (float)len);
            prev = end;
        }
    }

    // root term + bias + relu
    const float4* xs = (const float4*)(x + ((long)node << 4));
    float4 v0 = xs[0], v1 = xs[1], v2 = xs[2], v3 = xs[3];
    const float* wr = root1 + c;
    acc += b1[c];
    acc += v0.x * wr[0]   + v0.y * wr[32]  + v0.z * wr[64]  + v0.w * wr[96];
    acc += v1.x * wr[128] + v1.y * wr[160] + v1.z * wr[192] + v1.w * wr[224];
    acc += v2.x * wr[256] + v2.y * wr[288] + v2.z * wr[320] + v2.w * wr[352];
    acc += v3.x * wr[384] + v3.y * wr[416] + v3.z * wr[448] + v3.w * wr[480];
    h[(node << 5) + c] = fmaxf(acc, 0.0f);
}

// ---------------------------------------------------------------------------
// l1 fallback (ws too small for xW16): direct per-edge dot, weights in regs per (node,r)
// ---------------------------------------------------------------------------
__global__ __launch_bounds__(256) void l1_fb_kernel(const float* __restrict__ x,
                                                    const int* __restrict__ csr,
                                                    const int* __restrict__ ends,
                                                    const float* __restrict__ W1,
                                                    const float* __restrict__ root1,
                                                    const float* __restrict__ b1,
                                                    float* __restrict__ h, int N) {
    int gid  = blockIdx.x * 256 + threadIdx.x;
    int node = gid >> 5;
    int c    = gid & 31;
    if (node >= N) return;

    int4 e0 = ((const int4*)ends)[node * 2];
    int4 e1 = ((const int4*)ends)[node * 2 + 1];
    int end_r[N_REL] = {e0.x, e0.y, e0.z, e0.w, e1.x, e1.y, e1.z, e1.w};

    int prev = (node > 0) ? __ldg(&ends[node * N_REL - 1]) : 0;
    float acc = 0.0f;

#pragma unroll
    for (int r = 0; r < N_REL; ++r) {
        int end = end_r[r];
        int len = end - prev;
        if (len > 0) {
            const float* wp = W1 + (r * IN_CH) * HID_CH + c;
            float w[IN_CH];
#pragma unroll
            for (int f = 0; f < IN_CH; ++f) w[f] = wp[f * HID_CH];
            float seg = 0.0f;
            for (int p = prev; p < end; ++p) {
                int s = csr[p];
                const float4* xs = (const float4*)(x + ((long)s << 4));
                float4 v0 = xs[0], v1 = xs[1], v2 = xs[2], v3 = xs[3];
                float a;
                a  = v0.x * w[0]  + v0.y * w[1]  + v0.z * w[2]  + v0.w * w[3];
                a += v1.x * w[4]  + v1.y * w[5]  + v1.z * w[6]  + v1.w * w[7];
                a += v2.x * w[8]  + v2.y * w[9]  + v2.z * w[10] + v2.w * w[11];
                a += v3.x * w[12] + v3.y * w[13] + v3.z * w[14] + v3.w * w[15];
                seg += a;
            }
            acc += seg * (1.0f / (float)len);
            prev = end;
        }
    }

    const float4* xs = (const float4*)(x + ((long)node << 4));
    float4 v0 = xs[0], v1 = xs[1], v2 = xs[2], v3 = xs[3];
    const float* wr = root1 + c;
    acc += b1[c];
    acc += v0.x * wr[0]   + v0.y * wr[32]  + v0.z * wr[64]  + v0.w * wr[96];
    acc += v1.x * wr[128] + v1.y * wr[160] + v1.z * wr[192] + v1.w * wr[224];
    acc += v2.x * wr[256] + v2.y * wr[288] + v2.z * wr[320] + v2.w * wr[352];
    acc += v3.x * wr[384] + v3.y * wr[416] + v3.z * wr[448] + v3.w * wr[480];
    h[(node << 5) + c] = fmaxf(acc, 0.0f);
}

// ---------------------------------------------------------------------------
// hw: hW[n][r][o] = h[n] @ W2[r][:,o]   (r<8);  hroot[n][o] = h[n]@root2[:,o]+b2[o]
// one thread per (n, j), j in 0..8 (j==8 -> root)
// ---------------------------------------------------------------------------
__global__ __launch_bounds__(256) void hw_kernel(const float* __restrict__ h,
                                                 const float* __restrict__ W2,
                                                 const float* __restrict__ root2,
                                                 const float* __restrict__ b2,
                                                 float* __restrict__ hW,
                                                 float* __restrict__ hroot, int N) {
    int gid = blockIdx.x * 256 + threadIdx.x;
    if (gid >= N * 9) return;
    int n = gid / 9;
    int j = gid - n * 9;

    const float* hn = h + ((long)n << 5);
    const float* wp = (j < 8) ? (W2 + j * (HID_CH * OUT_CH)) : root2;

    float o0 = 0.0f, o1 = 0.0f;
#pragma unroll
    for (int f = 0; f < HID_CH; ++f) {
        float hf = hn[f];
        o0 += hf * wp[f * 2 + 0];
        o1 += hf * wp[f * 2 + 1];
    }
    if (j < 8) {
        *(float2*)(hW + ((long)n << 4) + (j << 1)) = make_float2(o0, o1);
    } else {
        *(float2*)(hroot + ((long)n << 1)) = make_float2(o0 + b2[0], o1 + b2[1]);
    }
}

// ---------------------------------------------------------------------------
// l2 finish: 8 lanes per node, lane = relation; gather hW pairs, reduce, softmax
// ---------------------------------------------------------------------------
__global__ __launch_bounds__(256) void l2_finish_kernel(const int* __restrict__ csr,
                                                        const int* __restrict__ ends,
                                                        const float* __restrict__ hW,
                                                        const float* __restrict__ hroot,
                                                        float* __restrict__ out, int N) {
    int gid  = blockIdx.x * 256 + threadIdx.x;
    int node = gid >> 3;
    int r    = gid & 7;
    if (node >= N) return;

    int idx  = node * N_REL + r;
    int prev = (idx > 0) ? ends[idx - 1] : 0;
    int end  = ends[idx];

    float o0 = 0.0f, o1 = 0.0f;
    if (end > prev) {
        float s0 = 0.0f, s1 = 0.0f;
        int p = prev;
        for (; p + 1 < end; p += 2) {
            int a = csr[p], b = csr[p + 1];
            float2 va = *(const float2*)(hW + ((long)a << 4) + (r << 1));
            float2 vb = *(const float2*)(hW + ((long)b << 4) + (r << 1));
            s0 += va.x + vb.x; s1 += va.y + vb.y;
        }
        if (p < end) {
            int a = csr[p];
            float2 va = *(const float2*)(hW + ((long)a << 4) + (r << 1));
            s0 += va.x; s1 += va.y;
        }
        float inv = 1.0f / (float)(end - prev);
        o0 = s0 * inv; o1 = s1 * inv;
    }

#pragma unroll
    for (int m = 1; m < 8; m <<= 1) {
        o0 += __shfl_xor(o0, m, 64);
        o1 += __shfl_xor(o1, m, 64);
    }

    if (r == 0) {
        float2 rt = *(const float2*)(hroot + ((long)node << 1));
        o0 += rt.x; o1 += rt.y;
        float mx = fmaxf(o0, o1);
        float l  = mx + logf(__expf(o0 - mx) + __expf(o1 - mx));
        *(float2*)(out + ((long)node << 1)) = make_float2(o0 - l, o1 - l);
    }
}

// ---------------------------------------------------------------------------
extern "C" void kernel_launch(void* const* d_in, const int* in_sizes, int n_in,
                              void* d_out, int out_size, void* d_ws, size_t ws_size,
                              hipStream_t stream) {
    const float* x     = (const float*)d_in[0];
    const int*   eidx  = (const int*)d_in[1];
    const int*   etype = (const int*)d_in[2];
    const float* W1    = (const float*)d_in[3];
    const float* root1 = (const float*)d_in[4];
    const float* b1    = (const float*)d_in[5];
    const float* W2    = (const float*)d_in[6];
    const float* root2 = (const float*)d_in[7];
    const float* b2    = (const float*)d_in[8];
    float* out = (float*)d_out;

    const int N = in_sizes[0] / IN_CH;
    const int E = in_sizes[2];
    const int M = N * N_REL;
    const int* src = eidx;
    const int* dst = eidx + E;

    char* wp = (char*)d_ws;
    auto take = [&](size_t bytes) {
        char* p = wp;
        wp += (bytes + 63) & ~(size_t)63;
        return p;
    };
    int*   ptr    = (int*)take((size_t)M * sizeof(int));
    int*   blksum = (int*)take(4096 * sizeof(int));
    int*   csr    = (int*)take((size_t)E * sizeof(int));
    float* h      = (float*)take((size_t)N * HID_CH * sizeof(float));
    float* hW     = (float*)take((size_t)N * 16 * sizeof(float));
    float* hroot  = (float*)take((size_t)N * 2 * sizeof(float));
    unsigned short* xW16 = (unsigned short*)take((size_t)N * N_REL * HID_CH * sizeof(unsigned short));
    bool use_xw = ((size_t)(wp - (char*)d_ws) <= ws_size);

    hipMemsetAsync(ptr, 0, (size_t)M * sizeof(int), stream);

    const int B = 256;
    const int nb = (M + 1023) / 1024;

    count_kernel<<<(E + B - 1) / B, B, 0, stream>>>(dst, etype, ptr, E);
    scan_a_kernel<<<nb, 1024, 0, stream>>>(ptr, blksum, M);
    scan_b_kernel<<<1, 64, 0, stream>>>(blksum, nb);
    scan_c_kernel<<<nb, 1024, 0, stream>>>(ptr, blksum, M);
    fill_kernel<<<(E + B - 1) / B, B, 0, stream>>>(src, dst, etype, ptr, csr, E);

    if (use_xw) {
        xw_kernel<<<(N + XW_TILE - 1) / XW_TILE, B, 0, stream>>>(x, W1, xW16, N);
        l1_gather_kernel<<<(N * 32 + B - 1) / B, B, 0, stream>>>(x, csr, ptr, xW16, root1, b1, h, N);
    } else {
        l1_fb_kernel<<<(N * 32 + B - 1) / B, B, 0, stream>>>(x, csr, ptr, W1, root1, b1, h, N);
    }

    hw_kernel<<<(N * 9 + B - 1) / B, B, 0, stream>>>(h, W2, root2, b2, hW, hroot, N);
    l2_finish_kernel<<<(N * 8 + B - 1) / B, B, 0, stream>>>(csr, ptr, hW, hroot, out, N);
}